// Round 19
// baseline (217.246 us; speedup 1.0000x reference)
//
#include <hip/hip_runtime.h>
#include <hip/hip_bf16.h>

#define BB 16
#define SS 2048
#define DD 2048
#define HH 16
#define HDIM 128
#define PAD_ID 50257
#define LN_EPS 1e-5f

// ---------- block reduction helpers (256 threads = 4 waves) ----------
__device__ __forceinline__ float block_sum256(float v, float* s4) {
    #pragma unroll
    for (int m = 32; m >= 1; m >>= 1) v += __shfl_xor(v, m, 64);
    __syncthreads();
    if ((threadIdx.x & 63) == 0) s4[threadIdx.x >> 6] = v;
    __syncthreads();
    return s4[0] + s4[1] + s4[2] + s4[3];
}
__device__ __forceinline__ float block_max256(float v, float* s4) {
    #pragma unroll
    for (int m = 32; m >= 1; m >>= 1) v = fmaxf(v, __shfl_xor(v, m, 64));
    __syncthreads();
    if ((threadIdx.x & 63) == 0) s4[threadIdx.x >> 6] = v;
    __syncthreads();
    return fmaxf(fmaxf(s4[0], s4[1]), fmaxf(s4[2], s4[3]));
}

// async global->LDS, 16B per lane (m97 pattern).
__device__ __forceinline__ void gl16(const float* g, float* l) {
    __builtin_amdgcn_global_load_lds(
        (const __attribute__((address_space(1))) void*)g,
        (__attribute__((address_space(3))) void*)l,
        16, 0, 0);
}

// bf16 pack/unpack (round-to-nearest-even), no type-API dependence
__device__ __forceinline__ unsigned short f2bf(float f) {
    unsigned int u = __float_as_uint(f);
    unsigned int r = (u + 0x7FFFu + ((u >> 16) & 1u)) >> 16;
    return (unsigned short)r;
}
__device__ __forceinline__ float bf2f(unsigned short us) {
    return __uint_as_float((unsigned int)us << 16);
}

// ---------- K0 (merged): y==0 -> last-non-pad + LN row -> xlast (blocks 0..15);
//                         y==1/2/3 -> broadcast-bias init of q/attn/out ----------
__global__ __launch_bounds__(256) void k_prep2(const float* __restrict__ hid, const int* __restrict__ ids,
                                               const float* __restrict__ g, const float* __restrict__ be,
                                               float* __restrict__ xlast,
                                               float* __restrict__ q, float* __restrict__ attn,
                                               float* __restrict__ out, const float* __restrict__ bq,
                                               const float* __restrict__ bv, const float* __restrict__ bo) {
    int which = blockIdx.y;
    int t = threadIdx.x;
    if (which != 0) {
        int i = blockIdx.x * 256 + t;
        float* dst = which == 1 ? q : (which == 2 ? attn : out);
        const float* bias = which == 1 ? bq : (which == 2 ? bv : bo);
        dst[i] = bias[i & (DD - 1)];
        return;
    }
    if (blockIdx.x >= 16) return;
    int b = blockIdx.x;
    __shared__ int sm[256];
    __shared__ float s4[4];
    const int* row = ids + (size_t)b * SS;
    int best = -1;
    for (int s = t; s < SS; s += 256)
        if (row[s] != PAD_ID) best = s;
    sm[t] = best;
    __syncthreads();
    for (int off = 128; off > 0; off >>= 1) {
        if (t < off) sm[t] = max(sm[t], sm[t + off]);
        __syncthreads();
    }
    int idx = (sm[0] < 0) ? 0 : sm[0];
    const float4* row4 = (const float4*)(hid + ((size_t)b * SS + idx) * DD);
    float4 v0 = row4[t], v1 = row4[t + 256];
    float s  = v0.x + v0.y + v0.z + v0.w + v1.x + v1.y + v1.z + v1.w;
    float sq = v0.x*v0.x + v0.y*v0.y + v0.z*v0.z + v0.w*v0.w
             + v1.x*v1.x + v1.y*v1.y + v1.z*v1.z + v1.w*v1.w;
    s  = block_sum256(s, s4);
    sq = block_sum256(sq, s4);
    float mu = s * (1.0f / DD);
    float rstd = rsqrtf(sq * (1.0f / DD) - mu * mu + LN_EPS);
    const float4* g4 = (const float4*)g;
    const float4* b4 = (const float4*)be;
    float4 ga = g4[t], gb = g4[t + 256], ba = b4[t], bb = b4[t + 256];
    float4 o0, o1;
    o0.x = (v0.x - mu) * rstd * ga.x + ba.x;  o0.y = (v0.y - mu) * rstd * ga.y + ba.y;
    o0.z = (v0.z - mu) * rstd * ga.z + ba.z;  o0.w = (v0.w - mu) * rstd * ga.w + ba.w;
    o1.x = (v1.x - mu) * rstd * gb.x + bb.x;  o1.y = (v1.y - mu) * rstd * gb.y + bb.y;
    o1.z = (v1.z - mu) * rstd * gb.z + bb.z;  o1.w = (v1.w - mu) * rstd * gb.w + bb.w;
    ((float4*)(xlast + (size_t)b * DD))[t]       = o0;
    ((float4*)(xlast + (size_t)b * DD))[t + 256] = o1;
}

// ---------- Kq: q[b,p] += sum_d xlast[b,d]*wq[d,p]; grid (8 ptiles, 32 kch) ----------
__global__ __launch_bounds__(256) void k_q(const float* __restrict__ xlast, const float* __restrict__ wq,
                                           float* __restrict__ q) {
    int ptile = blockIdx.x, kch = blockIdx.y, tid = threadIdx.x;
    __shared__ float xs[16][64];
    {
        int b = tid >> 4, c4 = tid & 15;
        *(float4*)&xs[b][c4 * 4] = *(const float4*)&xlast[(size_t)b * DD + kch * 64 + c4 * 4];
    }
    __syncthreads();
    int p = ptile * 256 + tid;
    float acc[16];
    #pragma unroll
    for (int b = 0; b < 16; b++) acc[b] = 0.f;
    for (int dd = 0; dd < 64; dd++) {
        float wqv = wq[(size_t)(kch * 64 + dd) * DD + p];
        #pragma unroll
        for (int b = 0; b < 16; b++) acc[b] = fmaf(xs[b][dd], wqv, acc[b]);
    }
    #pragma unroll
    for (int b = 0; b < 16; b++) atomicAdd(&q[(size_t)b * DD + p], acc[b]);
}

// ---------- Kt: t[b,h,d] = sum_j wk[d, h*128+j]*q[b, h*128+j]; tg = t*g[d] ----------
__global__ __launch_bounds__(256) void k_t(const float* __restrict__ wk, const float* __restrict__ q,
                                           const float* __restrict__ g, float* __restrict__ t_out,
                                           float* __restrict__ tg_out) {
    int d = blockIdx.x, tid = threadIdx.x;
    __shared__ float wkl[16 * 132];
    #pragma unroll
    for (int k = 0; k < 2; k++) {
        int f4 = tid + k * 256;
        int h = f4 >> 5, j4 = f4 & 31;
        *(float4*)&wkl[h * 132 + j4 * 4] = *(const float4*)&wk[(size_t)d * DD + h * 128 + j4 * 4];
    }
    __syncthreads();
    int b = tid >> 4, h = tid & 15;
    const float4* q4 = (const float4*)(q + (size_t)b * DD + h * 128);
    float acc = 0.f;
    #pragma unroll
    for (int j4 = 0; j4 < 32; j4++) {
        float4 qv = q4[j4];
        float4 wv4 = *(const float4*)&wkl[h * 132 + j4 * 4];
        acc = fmaf(qv.x, wv4.x, fmaf(qv.y, wv4.y, fmaf(qv.z, wv4.z, fmaf(qv.w, wv4.w, acc))));
    }
    size_t o = (size_t)(b * 16 + h) * DD + d;
    t_out[o] = acc;
    tg_out[o] = acc * g[d];
}

// ---------- KG: G1[bh]=sum_d tg ; wconst[bh]=sum_d beta*t + sum_j bk*q ----------
__global__ __launch_bounds__(256) void k_G(const float* __restrict__ t_in, const float* __restrict__ tg_in,
                                           const float* __restrict__ q, const float* __restrict__ lnb,
                                           const float* __restrict__ bk, float* __restrict__ G1,
                                           float* __restrict__ wconst) {
    int bh = blockIdx.x, tid = threadIdx.x;
    int b = bh >> 4, h = bh & 15;
    __shared__ float s4[4];
    const float4* tg4 = (const float4*)(tg_in + (size_t)bh * DD);
    const float4* t4  = (const float4*)(t_in + (size_t)bh * DD);
    const float4* lb4 = (const float4*)lnb;
    float g1p = 0.f, g2p = 0.f;
    #pragma unroll
    for (int k = 0; k < 2; k++) {
        int f = tid + k * 256;
        float4 a = tg4[f];
        g1p += a.x + a.y + a.z + a.w;
        float4 tv = t4[f];
        float4 bv = lb4[f];
        g2p = fmaf(tv.x, bv.x, fmaf(tv.y, bv.y, fmaf(tv.z, bv.z, fmaf(tv.w, bv.w, g2p))));
    }
    float cp = 0.f;
    if (tid < 128) cp = bk[h * 128 + tid] * q[(size_t)b * DD + h * 128 + tid];
    float G1v = block_sum256(g1p, s4);
    float rest = block_sum256(g2p + cp, s4);
    if (tid == 0) { G1[bh] = G1v; wconst[bh] = rest; }
}

// ---------- K1: fused LN-stats + 16-head logits, full D, 2 rows/thread.
// grid 1024 linear; XCD-aware bijective swizzle (T1). 3 full-size buffers +
// counted s_waitcnt vmcnt(6) + raw barrier (T3/T4).
__global__ __launch_bounds__(256) void k_logits15(const float* __restrict__ hid, const float* __restrict__ tg,
                                                  const float* __restrict__ G1, const float* __restrict__ wcst,
                                                  float* __restrict__ wout, float* __restrict__ muA,
                                                  float* __restrict__ rsA) {
    // x: 3 bufs of 32*128 at 0,4096,8192; tg: 3 bufs of 16*128 at 12288,14336,16384
    __shared__ float smem[18432];
    int lid = blockIdx.x;
    int swz = (lid & 7) * 128 + (lid >> 3);        // bijective (1024 % 8 == 0)
    int b = swz >> 6, st = swz & 63;
    int tid = threadIdx.x, qd = tid & 15, rp = tid >> 4;
    const float* hb = hid + ((size_t)b * SS + st * 32) * DD;
    const float* tgb = tg + (size_t)b * 16 * DD;

    float raw[2][16], sum[2], ssq[2];
    #pragma unroll
    for (int r = 0; r < 2; r++) {
        sum[r] = 0.f; ssq[r] = 0.f;
        #pragma unroll
        for (int h = 0; h < 16; h++) raw[r][h] = 0.f;
    }

    auto stage = [&](int c, int buf) {
        int d0 = c * 128;
        float* xd = smem + buf * 4096;
        float* td = smem + 12288 + buf * 2048;
        #pragma unroll
        for (int i = 0; i < 4; i++) {
            int f = i * 256 + tid;                 // float4 index in x tile (32x32)
            int row = f >> 5, c4 = f & 31;
            gl16(&hb[(size_t)row * DD + d0 + c4 * 4], &xd[f * 4]);
        }
        #pragma unroll
        for (int i = 0; i < 2; i++) {
            int f = i * 256 + tid;                 // float4 index in tg tile (16x32)
            int h = f >> 5, c4 = f & 31;
            gl16(&tgb[(size_t)h * DD + d0 + c4 * 4], &td[f * 4]);
        }
    };

    stage(0, 0);
    stage(1, 1);

    int cb = 0;                                    // compute buffer = c % 3
    #pragma unroll 1
    for (int c = 0; c < 16; c++) {
        if (c < 15) { asm volatile("s_waitcnt vmcnt(6)" ::: "memory"); }
        else        { asm volatile("s_waitcnt vmcnt(0)" ::: "memory"); }
        __builtin_amdgcn_s_barrier();
        asm volatile("" ::: "memory");             // pin LDS reads after the barrier
        if (c + 2 < 16) {
            int sb = cb + 2; if (sb >= 3) sb -= 3;
            stage(c + 2, sb);
        }
        const float* xb = smem + cb * 4096;
        const float* tb = smem + 12288 + cb * 2048;
        #pragma unroll
        for (int k = 0; k < 2; k++) {
            float4 x0 = *(const float4*)&xb[(rp * 2 + 0) * 128 + (qd + 16 * k) * 4];
            float4 x1 = *(const float4*)&xb[(rp * 2 + 1) * 128 + (qd + 16 * k) * 4];
            #pragma unroll
            for (int h = 0; h < 16; h++) {
                float4 tv = *(const float4*)&tb[h * 128 + (qd + 16 * k) * 4];
                raw[0][h] = fmaf(x0.x, tv.x, fmaf(x0.y, tv.y, fmaf(x0.z, tv.z, fmaf(x0.w, tv.w, raw[0][h]))));
                raw[1][h] = fmaf(x1.x, tv.x, fmaf(x1.y, tv.y, fmaf(x1.z, tv.z, fmaf(x1.w, tv.w, raw[1][h]))));
            }
            sum[0] += x0.x + x0.y + x0.z + x0.w;
            sum[1] += x1.x + x1.y + x1.z + x1.w;
            ssq[0] = fmaf(x0.x, x0.x, fmaf(x0.y, x0.y, fmaf(x0.z, x0.z, fmaf(x0.w, x0.w, ssq[0]))));
            ssq[1] = fmaf(x1.x, x1.x, fmaf(x1.y, x1.y, fmaf(x1.z, x1.z, fmaf(x1.w, x1.w, ssq[1]))));
        }
        cb = cb + 1; if (cb >= 3) cb -= 3;
    }
    __syncthreads();                               // all compute done before epilogue reuses smem

    // butterfly stats over the 16 qd lanes (lane bits 0..3)
    #pragma unroll
    for (int m = 1; m < 16; m <<= 1) {
        #pragma unroll
        for (int r = 0; r < 2; r++) {
            sum[r] += __shfl_xor(sum[r], m, 64);
            ssq[r] += __shfl_xor(ssq[r], m, 64);
        }
    }

    float g1 = G1[b * 16 + qd];
    float wc = wcst[b * 16 + qd];
    float* red = smem;                              // 256*17 = 4352 <= 18432
    #pragma unroll
    for (int rr = 0; rr < 2; rr++) {
        __syncthreads();
        #pragma unroll
        for (int h = 0; h < 16; h++) red[tid * 17 + h] = raw[rr][h];   // static reg idx, stride 17
        __syncthreads();
        float tot = 0.f;
        #pragma unroll
        for (int j = 0; j < 16; j++) tot += red[(rp * 16 + j) * 17 + qd];
        int s = st * 32 + rp * 2 + rr;
        float mu = sum[rr] * (1.0f / DD);
        float rstd = rsqrtf(ssq[rr] * (1.0f / DD) - mu * mu + LN_EPS);
        wout[(size_t)(b * 16 + qd) * SS + s] = rstd * (tot - mu * g1) + wc;
        if (qd == 0) { muA[(size_t)b * SS + s] = mu; rsA[(size_t)b * SS + s] = rstd; }
    }
}

// ---------- K2: softmax over s per (b,h); coef = p*rstd; M = sum coef*mu ----------
__global__ __launch_bounds__(256) void k_softmax(const float* __restrict__ wlog, const float* __restrict__ muA,
                                                 const float* __restrict__ rsA, float* __restrict__ coef,
                                                 float* __restrict__ Mout) {
    int bh = blockIdx.x, tid = threadIdx.x;
    int b = bh >> 4;
    __shared__ float s4[4];
    const float4* w4 = (const float4*)(wlog + (size_t)bh * SS);
    float4 v0 = w4[tid], v1 = w4[tid + 256];
    float mx = fmaxf(fmaxf(fmaxf(v0.x, v0.y), fmaxf(v0.z, v0.w)),
                     fmaxf(fmaxf(v1.x, v1.y), fmaxf(v1.z, v1.w)));
    mx = block_max256(mx, s4);
    float4 e0, e1;
    e0.x = __expf(v0.x - mx); e0.y = __expf(v0.y - mx); e0.z = __expf(v0.z - mx); e0.w = __expf(v0.w - mx);
    e1.x = __expf(v1.x - mx); e1.y = __expf(v1.y - mx); e1.z = __expf(v1.z - mx); e1.w = __expf(v1.w - mx);
    float ssum = e0.x + e0.y + e0.z + e0.w + e1.x + e1.y + e1.z + e1.w;
    ssum = block_sum256(ssum, s4);
    float inv = 1.0f / ssum;
    const float4* r4 = (const float4*)(rsA + (size_t)b * SS);
    const float4* m4 = (const float4*)(muA + (size_t)b * SS);
    float4 ra = r4[tid], rb = r4[tid + 256], ma = m4[tid], mb = m4[tid + 256];
    float4 c0, c1;
    c0.x = e0.x * inv * ra.x; c0.y = e0.y * inv * ra.y; c0.z = e0.z * inv * ra.z; c0.w = e0.w * inv * ra.w;
    c1.x = e1.x * inv * rb.x; c1.y = e1.y * inv * rb.y; c1.z = e1.z * inv * rb.z; c1.w = e1.w * inv * rb.w;
    ((float4*)(coef + (size_t)bh * SS))[tid] = c0;
    ((float4*)(coef + (size_t)bh * SS))[tid + 256] = c1;
    float Mp = c0.x * ma.x + c0.y * ma.y + c0.z * ma.z + c0.w * ma.w
             + c1.x * mb.x + c1.y * mb.y + c1.z * mb.z + c1.w * mb.w;
    Mp = block_sum256(Mp, s4);
    if (tid == 0) Mout[bh] = Mp;
}

// ---------- K3: Apart[ch][b][h][d] (bf16) = sum_{s in 64-chunk} coef*hid.
// grid (16 b, 2 dt, 32 ch) = 1024 blocks (4/CU, 16 waves/CU). float4 x loads,
// 8-deep register prefetch. bf16 store halves Apart footprint -> ch=32 fits
// the same 33.5 MB slot while doubling grid TLP.
__global__ __launch_bounds__(256) void k_pv8(const float* __restrict__ hid, const float* __restrict__ coef,
                                             unsigned short* __restrict__ Apart) {
    int b = blockIdx.x, dt = blockIdx.y, ch = blockIdx.z, tid = threadIdx.x;
    __shared__ float cl[64][16];
    int s0 = ch * 64;
    {
        // 256 threads: h = tid&15, s4 = tid>>4 (0..15): coef[(b*16+h)][s0+s4*4..+4]
        int h = tid & 15, sq = tid >> 4;
        float4 c4 = *(const float4*)&coef[(size_t)(b * 16 + h) * SS + s0 + sq * 4];
        cl[sq * 4 + 0][h] = c4.x; cl[sq * 4 + 1][h] = c4.y;
        cl[sq * 4 + 2][h] = c4.z; cl[sq * 4 + 3][h] = c4.w;
    }
    __syncthreads();
    int d = dt * 1024 + tid * 4;
    const float* hb = hid + ((size_t)b * SS + s0) * DD + d;
    float4 acc[16];
    #pragma unroll
    for (int h = 0; h < 16; h++) acc[h] = make_float4(0.f, 0.f, 0.f, 0.f);
    float4 xv[8];
    #pragma unroll
    for (int i = 0; i < 8; i++) xv[i] = *(const float4*)(hb + (size_t)i * DD);
    #pragma unroll 1
    for (int sb = 0; sb < 8; sb++) {
        #pragma unroll
        for (int i = 0; i < 8; i++) {
            int s = sb * 8 + i;
            float4 x = xv[i];
            if (sb < 7) xv[i] = *(const float4*)(hb + (size_t)(s + 8) * DD);
            float4 ca = *(const float4*)&cl[s][0];
            float4 cb = *(const float4*)&cl[s][4];
            float4 cc = *(const float4*)&cl[s][8];
            float4 cd = *(const float4*)&cl[s][12];
            acc[0].x = fmaf(ca.x, x.x, acc[0].x); acc[0].y = fmaf(ca.x, x.y, acc[0].y);
            acc[0].z = fmaf(ca.x, x.z, acc[0].z); acc[0].w = fmaf(ca.x, x.w, acc[0].w);
            acc[1].x = fmaf(ca.y, x.x, acc[1].x); acc[1].y = fmaf(ca.y, x.y, acc[1].y);
            acc[1].z = fmaf(ca.y, x.z, acc[1].z); acc[1].w = fmaf(ca.y, x.w, acc[1].w);
            acc[2].x = fmaf(ca.z, x.x, acc[2].x); acc[2].y = fmaf(ca.z, x.y, acc[2].y);
            acc[2].z = fmaf(ca.z, x.z, acc[2].z); acc[2].w = fmaf(ca.z, x.w, acc[2].w);
            acc[3].x = fmaf(ca.w, x.x, acc[3].x); acc[3].y = fmaf(ca.w, x.y, acc[3].y);
            acc[3].z = fmaf(ca.w, x.z, acc[3].z); acc[3].w = fmaf(ca.w, x.w, acc[3].w);
            acc[4].x = fmaf(cb.x, x.x, acc[4].x); acc[4].y = fmaf(cb.x, x.y, acc[4].y);
            acc[4].z = fmaf(cb.x, x.z, acc[4].z); acc[4].w = fmaf(cb.x, x.w, acc[4].w);
            acc[5].x = fmaf(cb.y, x.x, acc[5].x); acc[5].y = fmaf(cb.y, x.y, acc[5].y);
            acc[5].z = fmaf(cb.y, x.z, acc[5].z); acc[5].w = fmaf(cb.y, x.w, acc[5].w);
            acc[6].x = fmaf(cb.z, x.x, acc[6].x); acc[6].y = fmaf(cb.z, x.y, acc[6].y);
            acc[6].z = fmaf(cb.z, x.z, acc[6].z); acc[6].w = fmaf(cb.z, x.w, acc[6].w);
            acc[7].x = fmaf(cb.w, x.x, acc[7].x); acc[7].y = fmaf(cb.w, x.y, acc[7].y);
            acc[7].z = fmaf(cb.w, x.z, acc[7].z); acc[7].w = fmaf(cb.w, x.w, acc[7].w);
            acc[8].x = fmaf(cc.x, x.x, acc[8].x); acc[8].y = fmaf(cc.x, x.y, acc[8].y);
            acc[8].z = fmaf(cc.x, x.z, acc[8].z); acc[8].w = fmaf(cc.x, x.w, acc[8].w);
            acc[9].x = fmaf(cc.y, x.x, acc[9].x); acc[9].y = fmaf(cc.y, x.y, acc[9].y);
            acc[9].z = fmaf(cc.y, x.z, acc[9].z); acc[9].w = fmaf(cc.y, x.w, acc[9].w);
            acc[10].x = fmaf(cc.z, x.x, acc[10].x); acc[10].y = fmaf(cc.z, x.y, acc[10].y);
            acc[10].z = fmaf(cc.z, x.z, acc[10].z); acc[10].w = fmaf(cc.z, x.w, acc[10].w);
            acc[11].x = fmaf(cc.w, x.x, acc[11].x); acc[11].y = fmaf(cc.w, x.y, acc[11].y);
            acc[11].z = fmaf(cc.w, x.z, acc[11].z); acc[11].w = fmaf(cc.w, x.w, acc[11].w);
            acc[12].x = fmaf(cd.x, x.x, acc[12].x); acc[12].y = fmaf(cd.x, x.y, acc[12].y);
            acc[12].z = fmaf(cd.x, x.z, acc[12].z); acc[12].w = fmaf(cd.x, x.w, acc[12].w);
            acc[13].x = fmaf(cd.y, x.x, acc[13].x); acc[13].y = fmaf(cd.y, x.y, acc[13].y);
            acc[13].z = fmaf(cd.y, x.z, acc[13].z); acc[13].w = fmaf(cd.y, x.w, acc[13].w);
            acc[14].x = fmaf(cd.z, x.x, acc[14].x); acc[14].y = fmaf(cd.z, x.y, acc[14].y);
            acc[14].z = fmaf(cd.z, x.z, acc[14].z); acc[14].w = fmaf(cd.z, x.w, acc[14].w);
            acc[15].x = fmaf(cd.w, x.x, acc[15].x); acc[15].y = fmaf(cd.w, x.y, acc[15].y);
            acc[15].z = fmaf(cd.w, x.z, acc[15].z); acc[15].w = fmaf(cd.w, x.w, acc[15].w);
        }
    }
    #pragma unroll
    for (int h = 0; h < 16; h++) {
        ushort4 o;
        o.x = f2bf(acc[h].x); o.y = f2bf(acc[h].y);
        o.z = f2bf(acc[h].z); o.w = f2bf(acc[h].w);
        *(ushort4*)&Apart[((size_t)(ch * 16 + b) * 16 + h) * DD + d] = o;
    }
}

// ---------- K4a: attn[b, h*128+j] += sum_d y[b,h,d]*wv[d, h*128+j]; grid (16 h, 32 dc).
// Folds the 32-chunk bf16 Apart reduction into the y prologue.
__global__ __launch_bounds__(256) void k_attnv(const unsigned short* __restrict__ Apart, const float* __restrict__ M,
                                               const float* __restrict__ g, const float* __restrict__ be,
                                               const float* __restrict__ wv, float* __restrict__ attn) {
    int h = blockIdx.x, dc = blockIdx.y, tid = threadIdx.x;
    __shared__ float yl[16][64];
    int d0 = dc * 64;
    {
        int b = tid >> 4, c4 = tid & 15;
        float4 a4 = make_float4(0.f, 0.f, 0.f, 0.f);
        #pragma unroll
        for (int ch = 0; ch < 32; ch++) {
            ushort4 v = *(const ushort4*)&Apart[((size_t)(ch * 16 + b) * 16 + h) * DD + d0 + c4 * 4];
            a4.x += bf2f(v.x); a4.y += bf2f(v.y); a4.z += bf2f(v.z); a4.w += bf2f(v.w);
        }
        float4 g4 = *(const float4*)&g[d0 + c4 * 4];
        float4 b4 = *(const float4*)&be[d0 + c4 * 4];
        float m = M[b * 16 + h];
        float4 y;
        y.x = g4.x * (a4.x - m) + b4.x;  y.y = g4.y * (a4.y - m) + b4.y;
        y.z = g4.z * (a4.z - m) + b4.z;  y.w = g4.w * (a4.w - m) + b4.w;
        *(float4*)&yl[b][c4 * 4] = y;
    }
    __syncthreads();
    int j = tid & 127, h2 = tid >> 7;
    float acc[16];
    #pragma unroll
    for (int b = 0; b < 16; b++) acc[b] = 0.f;
    for (int dl = 0; dl < 32; dl++) {
        int dd = h2 * 32 + dl;
        float wvv = wv[(size_t)(d0 + dd) * DD + h * 128 + j];
        #pragma unroll
        for (int b = 0; b < 16; b++) acc[b] = fmaf(yl[b][dd], wvv, acc[b]);
    }
    #pragma unroll
    for (int b = 0; b < 16; b++) atomicAdd(&attn[(size_t)b * DD + h * 128 + j], acc[b]);
}

// ---------- K4b: out[b,p] += sum_c attn[b,c]*wo[c,p]; grid (8 ptiles, 32 cch) ----------
__global__ __launch_bounds__(256) void k_out(const float* __restrict__ attn, const float* __restrict__ wo,
                                             float* __restrict__ out) {
    int ptile = blockIdx.x, cch = blockIdx.y, tid = threadIdx.x;
    __shared__ float al[16][64];
    int c0 = cch * 64;
    {
        int b = tid >> 4, c4 = tid & 15;
        *(float4*)&al[b][c4 * 4] = *(const float4*)&attn[(size_t)b * DD + c0 + c4 * 4];
    }
    __syncthreads();
    int p = ptile * 256 + tid;
    float acc[16];
    #pragma unroll
    for (int b = 0; b < 16; b++) acc[b] = 0.f;
    for (int cc = 0; cc < 64; cc++) {
        float wov = wo[(size_t)(c0 + cc) * DD + p];
        #pragma unroll
        for (int b = 0; b < 16; b++) acc[b] = fmaf(al[b][cc], wov, acc[b]);
    }
    #pragma unroll
    for (int b = 0; b < 16; b++) atomicAdd(&out[(size_t)b * DD + p], acc[b]);
}

extern "C" void kernel_launch(void* const* d_in, const int* in_sizes, int n_in,
                              void* d_out, int out_size, void* d_ws, size_t ws_size,
                              hipStream_t stream) {
    const float* hid = (const float*)d_in[0];
    const int*   ids = (const int*)d_in[1];
    const float* lnw = (const float*)d_in[2];
    const float* lnb = (const float*)d_in[3];
    const float* wq  = (const float*)d_in[4];
    const float* bq  = (const float*)d_in[5];
    const float* wk  = (const float*)d_in[6];
    const float* bk  = (const float*)d_in[7];
    const float* wv  = (const float*)d_in[8];
    const float* bv  = (const float*)d_in[9];
    const float* wo  = (const float*)d_in[10];
    const float* bo  = (const float*)d_in[11];
    float* out = (float*)d_out;

    float* ws = (float*)d_ws;
    float* xlast = ws;                           // 32768
    float* q     = xlast + 32768;                // 32768
    float* t     = q + 32768;                    // 524288
    float* tg    = t + 524288;                   // 524288
    float* G1    = tg + 524288;                  // 256
    float* wcst  = G1 + 256;                     // 256
    float* wlog  = wcst + 256;                   // 524288
    float* muA   = wlog + 524288;                // 32768
    float* rsA   = muA + 32768;                  // 32768
    float* coef  = rsA + 32768;                  // 524288
    float* Mbh   = coef + 524288;                // 256
    float* Abh   = Mbh + 256;                    // 524288 (unused, kept for layout)
    float* attn  = Abh + 524288;                 // 32768
    unsigned short* Apart = (unsigned short*)(attn + 32768);  // 16.78M bf16 = 33.5 MB (same slot)

    k_prep2<<<dim3(128, 4), 256, 0, stream>>>(hid, ids, lnw, lnb, xlast, q, attn, out, bq, bv, bo);
    k_q<<<dim3(8, 32), 256, 0, stream>>>(xlast, wq, q);
    k_t<<<2048, 256, 0, stream>>>(wk, q, lnw, t, tg);
    k_G<<<256, 256, 0, stream>>>(t, tg, q, lnb, bk, G1, wcst);
    k_logits15<<<1024, 256, 0, stream>>>(hid, tg, G1, wcst, wlog, muA, rsA);
    k_softmax<<<256, 256, 0, stream>>>(wlog, muA, rsA, coef, Mbh);
    k_pv8<<<dim3(16, 2, 32), 256, 0, stream>>>(hid, coef, Apart);
    k_attnv<<<dim3(16, 32), 256, 0, stream>>>(Apart, Mbh, lnw, lnb, wv, attn);
    k_out<<<dim3(8, 32), 256, 0, stream>>>(attn, wo, out);
}

// Round 20
// 215.331 us; speedup vs baseline: 1.0089x; 1.0089x over previous
//
#include <hip/hip_runtime.h>
#include <hip/hip_bf16.h>

#define BB 16
#define SS 2048
#define DD 2048
#define HH 16
#define HDIM 128
#define PAD_ID 50257
#define LN_EPS 1e-5f

// ---------- block reduction helpers (256 threads = 4 waves) ----------
__device__ __forceinline__ float block_sum256(float v, float* s4) {
    #pragma unroll
    for (int m = 32; m >= 1; m >>= 1) v += __shfl_xor(v, m, 64);
    __syncthreads();
    if ((threadIdx.x & 63) == 0) s4[threadIdx.x >> 6] = v;
    __syncthreads();
    return s4[0] + s4[1] + s4[2] + s4[3];
}
__device__ __forceinline__ float block_max256(float v, float* s4) {
    #pragma unroll
    for (int m = 32; m >= 1; m >>= 1) v = fmaxf(v, __shfl_xor(v, m, 64));
    __syncthreads();
    if ((threadIdx.x & 63) == 0) s4[threadIdx.x >> 6] = v;
    __syncthreads();
    return fmaxf(fmaxf(s4[0], s4[1]), fmaxf(s4[2], s4[3]));
}

// async global->LDS, 16B per lane. LDS dest must be wave-uniform base + lane*16;
// our flat f = i*256+tid layout satisfies this exactly (m97 pattern).
__device__ __forceinline__ void gl16(const float* g, float* l) {
    __builtin_amdgcn_global_load_lds(
        (const __attribute__((address_space(1))) void*)g,
        (__attribute__((address_space(3))) void*)l,
        16, 0, 0);
}

// ---------- K0 (merged): y==0 -> last-non-pad + LN row -> xlast (blocks 0..15);
//                         y==1/2/3 -> broadcast-bias init of q/attn/out ----------
__global__ __launch_bounds__(256) void k_prep2(const float* __restrict__ hid, const int* __restrict__ ids,
                                               const float* __restrict__ g, const float* __restrict__ be,
                                               float* __restrict__ xlast,
                                               float* __restrict__ q, float* __restrict__ attn,
                                               float* __restrict__ out, const float* __restrict__ bq,
                                               const float* __restrict__ bv, const float* __restrict__ bo) {
    int which = blockIdx.y;
    int t = threadIdx.x;
    if (which != 0) {
        int i = blockIdx.x * 256 + t;
        float* dst = which == 1 ? q : (which == 2 ? attn : out);
        const float* bias = which == 1 ? bq : (which == 2 ? bv : bo);
        dst[i] = bias[i & (DD - 1)];
        return;
    }
    if (blockIdx.x >= 16) return;
    int b = blockIdx.x;
    __shared__ int sm[256];
    __shared__ float s4[4];
    const int* row = ids + (size_t)b * SS;
    int best = -1;
    for (int s = t; s < SS; s += 256)
        if (row[s] != PAD_ID) best = s;
    sm[t] = best;
    __syncthreads();
    for (int off = 128; off > 0; off >>= 1) {
        if (t < off) sm[t] = max(sm[t], sm[t + off]);
        __syncthreads();
    }
    int idx = (sm[0] < 0) ? 0 : sm[0];
    const float4* row4 = (const float4*)(hid + ((size_t)b * SS + idx) * DD);
    float4 v0 = row4[t], v1 = row4[t + 256];
    float s  = v0.x + v0.y + v0.z + v0.w + v1.x + v1.y + v1.z + v1.w;
    float sq = v0.x*v0.x + v0.y*v0.y + v0.z*v0.z + v0.w*v0.w
             + v1.x*v1.x + v1.y*v1.y + v1.z*v1.z + v1.w*v1.w;
    s  = block_sum256(s, s4);
    sq = block_sum256(sq, s4);
    float mu = s * (1.0f / DD);
    float rstd = rsqrtf(sq * (1.0f / DD) - mu * mu + LN_EPS);
    const float4* g4 = (const float4*)g;
    const float4* b4 = (const float4*)be;
    float4 ga = g4[t], gb = g4[t + 256], ba = b4[t], bb = b4[t + 256];
    float4 o0, o1;
    o0.x = (v0.x - mu) * rstd * ga.x + ba.x;  o0.y = (v0.y - mu) * rstd * ga.y + ba.y;
    o0.z = (v0.z - mu) * rstd * ga.z + ba.z;  o0.w = (v0.w - mu) * rstd * ga.w + ba.w;
    o1.x = (v1.x - mu) * rstd * gb.x + bb.x;  o1.y = (v1.y - mu) * rstd * gb.y + bb.y;
    o1.z = (v1.z - mu) * rstd * gb.z + bb.z;  o1.w = (v1.w - mu) * rstd * gb.w + bb.w;
    ((float4*)(xlast + (size_t)b * DD))[t]       = o0;
    ((float4*)(xlast + (size_t)b * DD))[t + 256] = o1;
}

// ---------- Kq: q[b,p] += sum_d xlast[b,d]*wq[d,p]; grid (8 ptiles, 32 kch) ----------
__global__ __launch_bounds__(256) void k_q(const float* __restrict__ xlast, const float* __restrict__ wq,
                                           float* __restrict__ q) {
    int ptile = blockIdx.x, kch = blockIdx.y, tid = threadIdx.x;
    __shared__ float xs[16][64];
    {
        int b = tid >> 4, c4 = tid & 15;
        *(float4*)&xs[b][c4 * 4] = *(const float4*)&xlast[(size_t)b * DD + kch * 64 + c4 * 4];
    }
    __syncthreads();
    int p = ptile * 256 + tid;
    float acc[16];
    #pragma unroll
    for (int b = 0; b < 16; b++) acc[b] = 0.f;
    for (int dd = 0; dd < 64; dd++) {
        float wqv = wq[(size_t)(kch * 64 + dd) * DD + p];
        #pragma unroll
        for (int b = 0; b < 16; b++) acc[b] = fmaf(xs[b][dd], wqv, acc[b]);
    }
    #pragma unroll
    for (int b = 0; b < 16; b++) atomicAdd(&q[(size_t)b * DD + p], acc[b]);
}

// ---------- Kt: t[b,h,d] = sum_j wk[d, h*128+j]*q[b, h*128+j]; tg = t*g[d] ----------
__global__ __launch_bounds__(256) void k_t(const float* __restrict__ wk, const float* __restrict__ q,
                                           const float* __restrict__ g, float* __restrict__ t_out,
                                           float* __restrict__ tg_out) {
    int d = blockIdx.x, tid = threadIdx.x;
    __shared__ float wkl[16 * 132];
    #pragma unroll
    for (int k = 0; k < 2; k++) {
        int f4 = tid + k * 256;
        int h = f4 >> 5, j4 = f4 & 31;
        *(float4*)&wkl[h * 132 + j4 * 4] = *(const float4*)&wk[(size_t)d * DD + h * 128 + j4 * 4];
    }
    __syncthreads();
    int b = tid >> 4, h = tid & 15;
    const float4* q4 = (const float4*)(q + (size_t)b * DD + h * 128);
    float acc = 0.f;
    #pragma unroll
    for (int j4 = 0; j4 < 32; j4++) {
        float4 qv = q4[j4];
        float4 wv4 = *(const float4*)&wkl[h * 132 + j4 * 4];
        acc = fmaf(qv.x, wv4.x, fmaf(qv.y, wv4.y, fmaf(qv.z, wv4.z, fmaf(qv.w, wv4.w, acc))));
    }
    size_t o = (size_t)(b * 16 + h) * DD + d;
    t_out[o] = acc;
    tg_out[o] = acc * g[d];
}

// ---------- KG: G1[bh]=sum_d tg ; wconst[bh]=sum_d beta*t + sum_j bk*q ----------
__global__ __launch_bounds__(256) void k_G(const float* __restrict__ t_in, const float* __restrict__ tg_in,
                                           const float* __restrict__ q, const float* __restrict__ lnb,
                                           const float* __restrict__ bk, float* __restrict__ G1,
                                           float* __restrict__ wconst) {
    int bh = blockIdx.x, tid = threadIdx.x;
    int b = bh >> 4, h = bh & 15;
    __shared__ float s4[4];
    const float4* tg4 = (const float4*)(tg_in + (size_t)bh * DD);
    const float4* t4  = (const float4*)(t_in + (size_t)bh * DD);
    const float4* lb4 = (const float4*)lnb;
    float g1p = 0.f, g2p = 0.f;
    #pragma unroll
    for (int k = 0; k < 2; k++) {
        int f = tid + k * 256;
        float4 a = tg4[f];
        g1p += a.x + a.y + a.z + a.w;
        float4 tv = t4[f];
        float4 bv = lb4[f];
        g2p = fmaf(tv.x, bv.x, fmaf(tv.y, bv.y, fmaf(tv.z, bv.z, fmaf(tv.w, bv.w, g2p))));
    }
    float cp = 0.f;
    if (tid < 128) cp = bk[h * 128 + tid] * q[(size_t)b * DD + h * 128 + tid];
    float G1v = block_sum256(g1p, s4);
    float rest = block_sum256(g2p + cp, s4);
    if (tid == 0) { G1[bh] = G1v; wconst[bh] = rest; }
}

// ---------- K1: fused LN-stats + 16-head logits, full D, 2 rows/thread.
// grid 1024 linear; XCD-aware bijective swizzle (T1): swz=(lid%8)*128+lid/8 ->
// each XCD owns 2 consecutive b's -> tg panels (256 KB) become L2-resident.
// 3 full-size buffers + counted s_waitcnt vmcnt(6) + raw barrier (T3/T4).
__global__ __launch_bounds__(256) void k_logits15(const float* __restrict__ hid, const float* __restrict__ tg,
                                                  const float* __restrict__ G1, const float* __restrict__ wcst,
                                                  float* __restrict__ wout, float* __restrict__ muA,
                                                  float* __restrict__ rsA) {
    // x: 3 bufs of 32*128 at 0,4096,8192; tg: 3 bufs of 16*128 at 12288,14336,16384
    __shared__ float smem[18432];
    int lid = blockIdx.x;
    int swz = (lid & 7) * 128 + (lid >> 3);        // bijective (1024 % 8 == 0)
    int b = swz >> 6, st = swz & 63;
    int tid = threadIdx.x, qd = tid & 15, rp = tid >> 4;
    const float* hb = hid + ((size_t)b * SS + st * 32) * DD;
    const float* tgb = tg + (size_t)b * 16 * DD;

    float raw[2][16], sum[2], ssq[2];
    #pragma unroll
    for (int r = 0; r < 2; r++) {
        sum[r] = 0.f; ssq[r] = 0.f;
        #pragma unroll
        for (int h = 0; h < 16; h++) raw[r][h] = 0.f;
    }

    auto stage = [&](int c, int buf) {
        int d0 = c * 128;
        float* xd = smem + buf * 4096;
        float* td = smem + 12288 + buf * 2048;
        #pragma unroll
        for (int i = 0; i < 4; i++) {
            int f = i * 256 + tid;                 // float4 index in x tile (32x32)
            int row = f >> 5, c4 = f & 31;
            gl16(&hb[(size_t)row * DD + d0 + c4 * 4], &xd[f * 4]);
        }
        #pragma unroll
        for (int i = 0; i < 2; i++) {
            int f = i * 256 + tid;                 // float4 index in tg tile (16x32)
            int h = f >> 5, c4 = f & 31;
            gl16(&tgb[(size_t)h * DD + d0 + c4 * 4], &td[f * 4]);
        }
    };

    stage(0, 0);
    stage(1, 1);

    int cb = 0;                                    // compute buffer = c % 3
    #pragma unroll 1
    for (int c = 0; c < 16; c++) {
        if (c < 15) { asm volatile("s_waitcnt vmcnt(6)" ::: "memory"); }
        else        { asm volatile("s_waitcnt vmcnt(0)" ::: "memory"); }
        __builtin_amdgcn_s_barrier();
        asm volatile("" ::: "memory");             // pin LDS reads after the barrier
        if (c + 2 < 16) {
            int sb = cb + 2; if (sb >= 3) sb -= 3;
            stage(c + 2, sb);
        }
        const float* xb = smem + cb * 4096;
        const float* tb = smem + 12288 + cb * 2048;
        #pragma unroll
        for (int k = 0; k < 2; k++) {
            float4 x0 = *(const float4*)&xb[(rp * 2 + 0) * 128 + (qd + 16 * k) * 4];
            float4 x1 = *(const float4*)&xb[(rp * 2 + 1) * 128 + (qd + 16 * k) * 4];
            #pragma unroll
            for (int h = 0; h < 16; h++) {
                float4 tv = *(const float4*)&tb[h * 128 + (qd + 16 * k) * 4];
                raw[0][h] = fmaf(x0.x, tv.x, fmaf(x0.y, tv.y, fmaf(x0.z, tv.z, fmaf(x0.w, tv.w, raw[0][h]))));
                raw[1][h] = fmaf(x1.x, tv.x, fmaf(x1.y, tv.y, fmaf(x1.z, tv.z, fmaf(x1.w, tv.w, raw[1][h]))));
            }
            sum[0] += x0.x + x0.y + x0.z + x0.w;
            sum[1] += x1.x + x1.y + x1.z + x1.w;
            ssq[0] = fmaf(x0.x, x0.x, fmaf(x0.y, x0.y, fmaf(x0.z, x0.z, fmaf(x0.w, x0.w, ssq[0]))));
            ssq[1] = fmaf(x1.x, x1.x, fmaf(x1.y, x1.y, fmaf(x1.z, x1.z, fmaf(x1.w, x1.w, ssq[1]))));
        }
        cb = cb + 1; if (cb >= 3) cb -= 3;
    }
    __syncthreads();                               // all compute done before epilogue reuses smem

    // butterfly stats over the 16 qd lanes (lane bits 0..3)
    #pragma unroll
    for (int m = 1; m < 16; m <<= 1) {
        #pragma unroll
        for (int r = 0; r < 2; r++) {
            sum[r] += __shfl_xor(sum[r], m, 64);
            ssq[r] += __shfl_xor(ssq[r], m, 64);
        }
    }

    float g1 = G1[b * 16 + qd];
    float wc = wcst[b * 16 + qd];
    float* red = smem;                              // 256*17 = 4352 <= 18432
    #pragma unroll
    for (int rr = 0; rr < 2; rr++) {
        __syncthreads();
        #pragma unroll
        for (int h = 0; h < 16; h++) red[tid * 17 + h] = raw[rr][h];   // static reg idx, stride 17
        __syncthreads();
        float tot = 0.f;
        #pragma unroll
        for (int j = 0; j < 16; j++) tot += red[(rp * 16 + j) * 17 + qd];
        int s = st * 32 + rp * 2 + rr;
        float mu = sum[rr] * (1.0f / DD);
        float rstd = rsqrtf(ssq[rr] * (1.0f / DD) - mu * mu + LN_EPS);
        wout[(size_t)(b * 16 + qd) * SS + s] = rstd * (tot - mu * g1) + wc;
        if (qd == 0) { muA[(size_t)b * SS + s] = mu; rsA[(size_t)b * SS + s] = rstd; }
    }
}

// ---------- K2: softmax over s per (b,h); coef = p*rstd; M = sum coef*mu ----------
__global__ __launch_bounds__(256) void k_softmax(const float* __restrict__ wlog, const float* __restrict__ muA,
                                                 const float* __restrict__ rsA, float* __restrict__ coef,
                                                 float* __restrict__ Mout) {
    int bh = blockIdx.x, tid = threadIdx.x;
    int b = bh >> 4;
    __shared__ float s4[4];
    const float4* w4 = (const float4*)(wlog + (size_t)bh * SS);
    float4 v0 = w4[tid], v1 = w4[tid + 256];
    float mx = fmaxf(fmaxf(fmaxf(v0.x, v0.y), fmaxf(v0.z, v0.w)),
                     fmaxf(fmaxf(v1.x, v1.y), fmaxf(v1.z, v1.w)));
    mx = block_max256(mx, s4);
    float4 e0, e1;
    e0.x = __expf(v0.x - mx); e0.y = __expf(v0.y - mx); e0.z = __expf(v0.z - mx); e0.w = __expf(v0.w - mx);
    e1.x = __expf(v1.x - mx); e1.y = __expf(v1.y - mx); e1.z = __expf(v1.z - mx); e1.w = __expf(v1.w - mx);
    float ssum = e0.x + e0.y + e0.z + e0.w + e1.x + e1.y + e1.z + e1.w;
    ssum = block_sum256(ssum, s4);
    float inv = 1.0f / ssum;
    const float4* r4 = (const float4*)(rsA + (size_t)b * SS);
    const float4* m4 = (const float4*)(muA + (size_t)b * SS);
    float4 ra = r4[tid], rb = r4[tid + 256], ma = m4[tid], mb = m4[tid + 256];
    float4 c0, c1;
    c0.x = e0.x * inv * ra.x; c0.y = e0.y * inv * ra.y; c0.z = e0.z * inv * ra.z; c0.w = e0.w * inv * ra.w;
    c1.x = e1.x * inv * rb.x; c1.y = e1.y * inv * rb.y; c1.z = e1.z * inv * rb.z; c1.w = e1.w * inv * rb.w;
    ((float4*)(coef + (size_t)bh * SS))[tid] = c0;
    ((float4*)(coef + (size_t)bh * SS))[tid + 256] = c1;
    float Mp = c0.x * ma.x + c0.y * ma.y + c0.z * ma.z + c0.w * ma.w
             + c1.x * mb.x + c1.y * mb.y + c1.z * mb.z + c1.w * mb.w;
    Mp = block_sum256(Mp, s4);
    if (tid == 0) Mout[bh] = Mp;
}

// ---------- K3: Apart[ch][b][h][d] = sum_{s in chunk} coef*hid.
// grid (16 b, 2 dt, 16 ch). Thread owns float4 column; coef read as b128 broadcast.
// 8-deep register prefetch of x.
__global__ __launch_bounds__(256) void k_pv6(const float* __restrict__ hid, const float* __restrict__ coef,
                                             float* __restrict__ Apart) {
    int b = blockIdx.x, dt = blockIdx.y, ch = blockIdx.z, tid = threadIdx.x;
    __shared__ float cl[128][16];
    int s0 = ch * 128;
    #pragma unroll
    for (int k = 0; k < 2; k++) {
        int f = tid + k * 256; int h = f >> 5, s4i = f & 31;
        float4 c4 = *(const float4*)&coef[(size_t)(b * 16 + h) * SS + s0 + s4i * 4];
        cl[s4i * 4 + 0][h] = c4.x; cl[s4i * 4 + 1][h] = c4.y;
        cl[s4i * 4 + 2][h] = c4.z; cl[s4i * 4 + 3][h] = c4.w;
    }
    __syncthreads();
    int d = dt * 1024 + tid * 4;
    const float* hb = hid + ((size_t)b * SS + s0) * DD + d;
    float4 acc[16];
    #pragma unroll
    for (int h = 0; h < 16; h++) acc[h] = make_float4(0.f, 0.f, 0.f, 0.f);
    float4 xv[8];
    #pragma unroll
    for (int i = 0; i < 8; i++) xv[i] = *(const float4*)(hb + (size_t)i * DD);
    #pragma unroll 1
    for (int sb = 0; sb < 16; sb++) {
        #pragma unroll
        for (int i = 0; i < 8; i++) {
            int s = sb * 8 + i;
            float4 x = xv[i];
            if (sb < 15) xv[i] = *(const float4*)(hb + (size_t)(s + 8) * DD);
            float4 ca = *(const float4*)&cl[s][0];
            float4 cb = *(const float4*)&cl[s][4];
            float4 cc = *(const float4*)&cl[s][8];
            float4 cd = *(const float4*)&cl[s][12];
            acc[0].x = fmaf(ca.x, x.x, acc[0].x); acc[0].y = fmaf(ca.x, x.y, acc[0].y);
            acc[0].z = fmaf(ca.x, x.z, acc[0].z); acc[0].w = fmaf(ca.x, x.w, acc[0].w);
            acc[1].x = fmaf(ca.y, x.x, acc[1].x); acc[1].y = fmaf(ca.y, x.y, acc[1].y);
            acc[1].z = fmaf(ca.y, x.z, acc[1].z); acc[1].w = fmaf(ca.y, x.w, acc[1].w);
            acc[2].x = fmaf(ca.z, x.x, acc[2].x); acc[2].y = fmaf(ca.z, x.y, acc[2].y);
            acc[2].z = fmaf(ca.z, x.z, acc[2].z); acc[2].w = fmaf(ca.z, x.w, acc[2].w);
            acc[3].x = fmaf(ca.w, x.x, acc[3].x); acc[3].y = fmaf(ca.w, x.y, acc[3].y);
            acc[3].z = fmaf(ca.w, x.z, acc[3].z); acc[3].w = fmaf(ca.w, x.w, acc[3].w);
            acc[4].x = fmaf(cb.x, x.x, acc[4].x); acc[4].y = fmaf(cb.x, x.y, acc[4].y);
            acc[4].z = fmaf(cb.x, x.z, acc[4].z); acc[4].w = fmaf(cb.x, x.w, acc[4].w);
            acc[5].x = fmaf(cb.y, x.x, acc[5].x); acc[5].y = fmaf(cb.y, x.y, acc[5].y);
            acc[5].z = fmaf(cb.y, x.z, acc[5].z); acc[5].w = fmaf(cb.y, x.w, acc[5].w);
            acc[6].x = fmaf(cb.z, x.x, acc[6].x); acc[6].y = fmaf(cb.z, x.y, acc[6].y);
            acc[6].z = fmaf(cb.z, x.z, acc[6].z); acc[6].w = fmaf(cb.z, x.w, acc[6].w);
            acc[7].x = fmaf(cb.w, x.x, acc[7].x); acc[7].y = fmaf(cb.w, x.y, acc[7].y);
            acc[7].z = fmaf(cb.w, x.z, acc[7].z); acc[7].w = fmaf(cb.w, x.w, acc[7].w);
            acc[8].x = fmaf(cc.x, x.x, acc[8].x); acc[8].y = fmaf(cc.x, x.y, acc[8].y);
            acc[8].z = fmaf(cc.x, x.z, acc[8].z); acc[8].w = fmaf(cc.x, x.w, acc[8].w);
            acc[9].x = fmaf(cc.y, x.x, acc[9].x); acc[9].y = fmaf(cc.y, x.y, acc[9].y);
            acc[9].z = fmaf(cc.y, x.z, acc[9].z); acc[9].w = fmaf(cc.y, x.w, acc[9].w);
            acc[10].x = fmaf(cc.z, x.x, acc[10].x); acc[10].y = fmaf(cc.z, x.y, acc[10].y);
            acc[10].z = fmaf(cc.z, x.z, acc[10].z); acc[10].w = fmaf(cc.z, x.w, acc[10].w);
            acc[11].x = fmaf(cc.w, x.x, acc[11].x); acc[11].y = fmaf(cc.w, x.y, acc[11].y);
            acc[11].z = fmaf(cc.w, x.z, acc[11].z); acc[11].w = fmaf(cc.w, x.w, acc[11].w);
            acc[12].x = fmaf(cd.x, x.x, acc[12].x); acc[12].y = fmaf(cd.x, x.y, acc[12].y);
            acc[12].z = fmaf(cd.x, x.z, acc[12].z); acc[12].w = fmaf(cd.x, x.w, acc[12].w);
            acc[13].x = fmaf(cd.y, x.x, acc[13].x); acc[13].y = fmaf(cd.y, x.y, acc[13].y);
            acc[13].z = fmaf(cd.y, x.z, acc[13].z); acc[13].w = fmaf(cd.y, x.w, acc[13].w);
            acc[14].x = fmaf(cd.z, x.x, acc[14].x); acc[14].y = fmaf(cd.z, x.y, acc[14].y);
            acc[14].z = fmaf(cd.z, x.z, acc[14].z); acc[14].w = fmaf(cd.z, x.w, acc[14].w);
            acc[15].x = fmaf(cd.w, x.x, acc[15].x); acc[15].y = fmaf(cd.w, x.y, acc[15].y);
            acc[15].z = fmaf(cd.w, x.z, acc[15].z); acc[15].w = fmaf(cd.w, x.w, acc[15].w);
        }
    }
    #pragma unroll
    for (int h = 0; h < 16; h++)
        *(float4*)&Apart[((size_t)(ch * 16 + b) * 16 + h) * DD + d] = acc[h];
}

// ---------- K4a: attn[b, h*128+j] += sum_d y[b,h,d]*wv[d, h*128+j]; grid (16 h, 32 dc).
// Folds the chunk reduction of Apart into the y prologue.
__global__ __launch_bounds__(256) void k_attnv(const float* __restrict__ Apart, const float* __restrict__ M,
                                               const float* __restrict__ g, const float* __restrict__ be,
                                               const float* __restrict__ wv, float* __restrict__ attn) {
    int h = blockIdx.x, dc = blockIdx.y, tid = threadIdx.x;
    __shared__ float yl[16][64];
    int d0 = dc * 64;
    {
        int b = tid >> 4, c4 = tid & 15;
        float4 a4 = make_float4(0.f, 0.f, 0.f, 0.f);
        #pragma unroll
        for (int ch = 0; ch < 16; ch++) {
            float4 v = *(const float4*)&Apart[((size_t)(ch * 16 + b) * 16 + h) * DD + d0 + c4 * 4];
            a4.x += v.x; a4.y += v.y; a4.z += v.z; a4.w += v.w;
        }
        float4 g4 = *(const float4*)&g[d0 + c4 * 4];
        float4 b4 = *(const float4*)&be[d0 + c4 * 4];
        float m = M[b * 16 + h];
        float4 y;
        y.x = g4.x * (a4.x - m) + b4.x;  y.y = g4.y * (a4.y - m) + b4.y;
        y.z = g4.z * (a4.z - m) + b4.z;  y.w = g4.w * (a4.w - m) + b4.w;
        *(float4*)&yl[b][c4 * 4] = y;
    }
    __syncthreads();
    int j = tid & 127, h2 = tid >> 7;
    float acc[16];
    #pragma unroll
    for (int b = 0; b < 16; b++) acc[b] = 0.f;
    for (int dl = 0; dl < 32; dl++) {
        int dd = h2 * 32 + dl;
        float wvv = wv[(size_t)(d0 + dd) * DD + h * 128 + j];
        #pragma unroll
        for (int b = 0; b < 16; b++) acc[b] = fmaf(yl[b][dd], wvv, acc[b]);
    }
    #pragma unroll
    for (int b = 0; b < 16; b++) atomicAdd(&attn[(size_t)b * DD + h * 128 + j], acc[b]);
}

// ---------- K4b: out[b,p] += sum_c attn[b,c]*wo[c,p]; grid (8 ptiles, 32 cch) ----------
__global__ __launch_bounds__(256) void k_out(const float* __restrict__ attn, const float* __restrict__ wo,
                                             float* __restrict__ out) {
    int ptile = blockIdx.x, cch = blockIdx.y, tid = threadIdx.x;
    __shared__ float al[16][64];
    int c0 = cch * 64;
    {
        int b = tid >> 4, c4 = tid & 15;
        *(float4*)&al[b][c4 * 4] = *(const float4*)&attn[(size_t)b * DD + c0 + c4 * 4];
    }
    __syncthreads();
    int p = ptile * 256 + tid;
    float acc[16];
    #pragma unroll
    for (int b = 0; b < 16; b++) acc[b] = 0.f;
    for (int cc = 0; cc < 64; cc++) {
        float wov = wo[(size_t)(c0 + cc) * DD + p];
        #pragma unroll
        for (int b = 0; b < 16; b++) acc[b] = fmaf(al[b][cc], wov, acc[b]);
    }
    #pragma unroll
    for (int b = 0; b < 16; b++) atomicAdd(&out[(size_t)b * DD + p], acc[b]);
}

extern "C" void kernel_launch(void* const* d_in, const int* in_sizes, int n_in,
                              void* d_out, int out_size, void* d_ws, size_t ws_size,
                              hipStream_t stream) {
    const float* hid = (const float*)d_in[0];
    const int*   ids = (const int*)d_in[1];
    const float* lnw = (const float*)d_in[2];
    const float* lnb = (const float*)d_in[3];
    const float* wq  = (const float*)d_in[4];
    const float* bq  = (const float*)d_in[5];
    const float* wk  = (const float*)d_in[6];
    const float* bk  = (const float*)d_in[7];
    const float* wv  = (const float*)d_in[8];
    const float* bv  = (const float*)d_in[9];
    const float* wo  = (const float*)d_in[10];
    const float* bo  = (const float*)d_in[11];
    float* out = (float*)d_out;

    float* ws = (float*)d_ws;
    float* xlast = ws;                           // 32768
    float* q     = xlast + 32768;                // 32768
    float* t     = q + 32768;                    // 524288
    float* tg    = t + 524288;                   // 524288
    float* G1    = tg + 524288;                  // 256
    float* wcst  = G1 + 256;                     // 256
    float* wlog  = wcst + 256;                   // 524288
    float* muA   = wlog + 524288;                // 32768
    float* rsA   = muA + 32768;                  // 32768
    float* coef  = rsA + 32768;                  // 524288
    float* Mbh   = coef + 524288;                // 256
    float* Abh   = Mbh + 256;                    // 524288 (unused, kept for layout)
    float* attn  = Abh + 524288;                 // 32768
    float* Apart = attn + 32768;                 // 8388608

    k_prep2<<<dim3(128, 4), 256, 0, stream>>>(hid, ids, lnw, lnb, xlast, q, attn, out, bq, bv, bo);
    k_q<<<dim3(8, 32), 256, 0, stream>>>(xlast, wq, q);
    k_t<<<2048, 256, 0, stream>>>(wk, q, lnw, t, tg);
    k_G<<<256, 256, 0, stream>>>(t, tg, q, lnb, bk, G1, wcst);
    k_logits15<<<1024, 256, 0, stream>>>(hid, tg, G1, wcst, wlog, muA, rsA);
    k_softmax<<<256, 256, 0, stream>>>(wlog, muA, rsA, coef, Mbh);
    k_pv6<<<dim3(16, 2, 16), 256, 0, stream>>>(hid, coef, Apart);
    k_attnv<<<dim3(16, 32), 256, 0, stream>>>(Apart, Mbh, lnw, lnb, wv, attn);
    k_out<<<dim3(8, 32), 256, 0, stream>>>(attn, wo, out);
}